// Round 4
// baseline (436.045 us; speedup 1.0000x reference)
//
#include <hip/hip_runtime.h>
#include <cmath>

// ConformalModelLogits forward (randomized=True, allow_zero_sets=False).
// One 64-lane wave per row. C=1000 -> 250 float4 chunks; lane l owns chunks
// {l, l+64, l+128, l+192} = 16 classes in registers. No LDS, no barriers.
//
// Algorithm: the membership condition cumsum[k]+pcs[k] <= tau is nondecreasing
// in k (scores >= 0, penalties >= 0), so qualifying positions form a prefix;
// with penalties=0.2 beyond class 5 the prefix length is <= 9, so iterative
// wave-argmax extraction terminates after ~10 steps instead of a full
// 1000-element sort. Softmax, threshold scan, randomized shrink, and all three
// outputs (logits copy, dense mask, sizes) are fused into one memory pass.

__global__ __launch_bounds__(256) void conformal_kernel(
    const float* __restrict__ logits,
    const float* __restrict__ penalties,
    const float* __restrict__ u,
    const float* __restrict__ Tptr,
    const float* __restrict__ Qptr,
    float* __restrict__ outL,
    float* __restrict__ outM,
    float* __restrict__ outS,
    int B, int C)
{
    const int lane = threadIdx.x & 63;
    const int row  = blockIdx.x * 4 + (threadIdx.x >> 6);
    if (row >= B) return;

    const float tau = Qptr[0];
    const float Tv  = Tptr[0];
    const int   nch = C >> 2;                  // 250 float4 chunks per row
    const float4* xrow4 = reinterpret_cast<const float4*>(logits + (size_t)row * C);

    float4 xv[4];
    float  sc[16];
    bool   valid[4];

    // ---- load + z = x/T, row max ----
    float m = -INFINITY;
    #pragma unroll
    for (int s = 0; s < 4; ++s) {
        const int ch = lane + (s << 6);
        valid[s] = (ch < nch);
        if (valid[s]) {
            const float4 q = xrow4[ch];
            xv[s] = q;
            const float z0 = q.x / Tv, z1 = q.y / Tv, z2 = q.z / Tv, z3 = q.w / Tv;
            sc[s*4+0] = z0; sc[s*4+1] = z1; sc[s*4+2] = z2; sc[s*4+3] = z3;
            m = fmaxf(m, fmaxf(fmaxf(z0, z1), fmaxf(z2, z3)));
        } else {
            xv[s] = make_float4(0.f, 0.f, 0.f, 0.f);
            sc[s*4+0] = -INFINITY; sc[s*4+1] = -INFINITY;
            sc[s*4+2] = -INFINITY; sc[s*4+3] = -INFINITY;
        }
    }
    #pragma unroll
    for (int off = 32; off > 0; off >>= 1)
        m = fmaxf(m, __shfl_xor(m, off, 64));

    // ---- exp + sum -> softmax scores ----
    float sum = 0.f;
    #pragma unroll
    for (int i = 0; i < 16; ++i) {
        const float e = expf(sc[i] - m);       // -INF tail -> 0
        sc[i] = e;
        sum += e;
    }
    #pragma unroll
    for (int off = 32; off > 0; off >>= 1)
        sum += __shfl_xor(sum, off, 64);
    #pragma unroll
    for (int i = 0; i < 16; ++i)
        sc[i] = sc[i] / sum;                   // exact IEEE div, matches jax

    // ---- iterative argmax extraction with early termination ----
    // rem: per-lane bitmask of remaining VALID slots only (invalid tail slots
    // carry score 0 and a class id >= C; they must never enter the argmax).
    unsigned rem = 0u;
    #pragma unroll
    for (int s = 0; s < 4; ++s)
        if (valid[s]) rem |= (0xFu << (s << 2));
    unsigned memb = 0u;                        // per-lane extracted slots
    float lv; int li;

    auto rescan = [&]() {
        lv = -1.0f; li = 0x7FFFFFFF;
        #pragma unroll
        for (int i = 0; i < 16; ++i) {
            if (rem & (1u << i)) {
                const int s = i >> 2, j = i & 3;
                const int cls = ((lane + (s << 6)) << 2) + j;
                const float v = sc[i];
                if (v > lv || (v == lv && cls < li)) { lv = v; li = cls; }
            }
        }
    };
    rescan();

    float cum = 0.f, pen = 0.f;
    int   k = 0;
    int   szb, last_idx;
    float V;

    while (true) {
        // wave argmax: larger score wins, ties -> smaller class index (stable,
        // matching jnp.argsort(-scores) tie order)
        float val = lv; int idx = li;
        #pragma unroll
        for (int off = 32; off > 0; off >>= 1) {
            const float ov = __shfl_xor(val, off, 64);
            const int   oi = __shfl_xor(idx, off, 64);
            if (ov > val || (ov == val && oi < idx)) { val = ov; idx = oi; }
        }
        // mark extracted (sorted position k); owning lane refreshes local max
        {
            const int ch = idx >> 2;
            if ((ch & 63) == lane) {
                const int slot = ((ch >> 6) << 2) | (idx & 3);
                rem  &= ~(1u << slot);
                memb |=  (1u << slot);
                rescan();
            }
        }
        last_idx = idx;
        const float penk = pen + penalties[k];         // pcs[k]
        if (cum + val + penk <= tau) {
            cum += val; pen = penk; ++k;
            if (k >= C) {                              // all positions passed
                szb = C;
                V = (tau - (cum - val) - penk) / val;  // idx = C-1
                break;
            }
        } else {
            szb = k + 1;                               // first failure at k
            V = (tau - cum - penk) / val;              // cum_s - ord_s = cum
            break;
        }
    }

    // ---- randomized shrink, clamps ----
    const float uu = u[row];
    int sizes = szb - ((uu >= V) ? 1 : 0);
    const bool full = (tau == 1.0f);
    if (full) sizes = C;
    if (sizes < 1) sizes = 1;
    const bool drop_last = (!full) && (sizes < szb);

    // ---- fused outputs: logits copy, mask, sizes ----
    float4* oL4 = reinterpret_cast<float4*>(outL + (size_t)row * C);
    float4* oM4 = reinterpret_cast<float4*>(outM + (size_t)row * C);
    #pragma unroll
    for (int s = 0; s < 4; ++s) {
        const int ch = lane + (s << 6);
        if (!valid[s]) continue;
        oL4[ch] = xv[s];
        float4 mk;
        float* mp = &mk.x;
        #pragma unroll
        for (int j = 0; j < 4; ++j) {
            const int slot = (s << 2) | j;
            const int cls  = (ch << 2) | j;
            const bool in_set = full ||
                (((memb >> slot) & 1u) && !(drop_last && cls == last_idx));
            mp[j] = in_set ? 1.0f : 0.0f;
        }
        oM4[ch] = mk;
    }
    if (lane == 0) outS[row] = (float)sizes;
}

extern "C" void kernel_launch(void* const* d_in, const int* in_sizes, int n_in,
                              void* d_out, int out_size, void* d_ws, size_t ws_size,
                              hipStream_t stream) {
    const float* logits    = (const float*)d_in[0];
    const float* penalties = (const float*)d_in[1];
    const float* u         = (const float*)d_in[2];
    const float* T         = (const float*)d_in[3];
    const float* Qhat      = (const float*)d_in[4];

    const int C = in_sizes[1];   // penalties: (1, C)
    const int B = in_sizes[2];   // u: (B,)

    float* out  = (float*)d_out;
    float* outL = out;                              // [B*C] logits pass-through
    float* outM = out + (size_t)B * C;              // [B*C] set mask as float
    float* outS = out + 2 * (size_t)B * C;          // [B]   sizes as float

    const int blocks = (B + 3) / 4;                 // 4 rows (waves) per block
    conformal_kernel<<<blocks, 256, 0, stream>>>(
        logits, penalties, u, T, Qhat, outL, outM, outS, B, C);
}

// Round 5
// 372.403 us; speedup vs baseline: 1.1709x; 1.1709x over previous
//
#include <hip/hip_runtime.h>
#include <cmath>

// ConformalModelLogits forward (randomized=True, allow_zero_sets=False).
// One 64-lane wave per row. C=1000 -> 250 float4 chunks; lane l owns chunks
// {l, l+64, l+128, l+192} = 16 classes in registers. No LDS tiles, no barriers.
//
// The membership condition cumsum[k]+pcs[k] <= tau is nondecreasing in k, so
// the prediction set is a sorted-prefix; penalties bound its length (<=10 for
// these inputs), so iterative wave-argmax extraction replaces the full sort.
//
// R4 (first measured round, 180us @ VALUBusy 73.6%): extraction loop was the
// VALU hog (divergent 16-slot rescan every pop + dependent penalties[k] load).
// This round: u64 packed-key butterfly (score_bits<<32 | ~cls), per-lane top-2
// precompute so refill is O(1) (full rescan only on a lane's 3rd pop), and
// penalties[k] served by ds_bpermute from a preloaded register.
// Softmax / cumsum / output code is byte-identical to the absmax=0.0 round.

__global__ __launch_bounds__(256) void conformal_kernel(
    const float* __restrict__ logits,
    const float* __restrict__ penalties,
    const float* __restrict__ u,
    const float* __restrict__ Tptr,
    const float* __restrict__ Qptr,
    float* __restrict__ outL,
    float* __restrict__ outM,
    float* __restrict__ outS,
    int B, int C)
{
    const int lane = threadIdx.x & 63;
    const int row  = blockIdx.x * 4 + (threadIdx.x >> 6);
    if (row >= B) return;

    const float tau = Qptr[0];
    const float Tv  = Tptr[0];
    const int   nch = C >> 2;                  // 250 float4 chunks per row
    const float4* xrow4 = reinterpret_cast<const float4*>(logits + (size_t)row * C);

    // early, latency-hidden scalar-ish loads
    const float pl = penalties[lane < C ? lane : 0];   // pcs increments via shfl
    const float uu = u[row];

    float4 xv[4];
    float  sc[16];
    bool   valid[4];

    // ---- load + z = x/T, row max ----  (byte-identical numerics path)
    float m = -INFINITY;
    #pragma unroll
    for (int s = 0; s < 4; ++s) {
        const int ch = lane + (s << 6);
        valid[s] = (ch < nch);
        if (valid[s]) {
            const float4 q = xrow4[ch];
            xv[s] = q;
            const float z0 = q.x / Tv, z1 = q.y / Tv, z2 = q.z / Tv, z3 = q.w / Tv;
            sc[s*4+0] = z0; sc[s*4+1] = z1; sc[s*4+2] = z2; sc[s*4+3] = z3;
            m = fmaxf(m, fmaxf(fmaxf(z0, z1), fmaxf(z2, z3)));
        } else {
            xv[s] = make_float4(0.f, 0.f, 0.f, 0.f);
            sc[s*4+0] = -INFINITY; sc[s*4+1] = -INFINITY;
            sc[s*4+2] = -INFINITY; sc[s*4+3] = -INFINITY;
        }
    }
    #pragma unroll
    for (int off = 32; off > 0; off >>= 1)
        m = fmaxf(m, __shfl_xor(m, off, 64));

    // ---- exp + sum -> softmax scores ----
    float sum = 0.f;
    #pragma unroll
    for (int i = 0; i < 16; ++i) {
        const float e = expf(sc[i] - m);       // -INF tail -> 0
        sc[i] = e;
        sum += e;
    }
    #pragma unroll
    for (int off = 32; off > 0; off >>= 1)
        sum += __shfl_xor(sum, off, 64);
    #pragma unroll
    for (int i = 0; i < 16; ++i)
        sc[i] = sc[i] / sum;                   // exact IEEE div, matches jax

    // ---- per-lane top-2 precompute on packed u64 keys ----
    // key = (float_bits(score) << 32) | (0xFFFFFFFF - cls): scores >= 0 so bit
    // order == value order; ties resolve to smaller class (argsort-stable).
    unsigned rem = 0u;
    #pragma unroll
    for (int s = 0; s < 4; ++s)
        if (valid[s]) rem |= (0xFu << (s << 2));
    unsigned memb = 0u;

    unsigned long long k1 = 0ull, k2 = 0ull;   // every lane has >=12 valid slots
    #pragma unroll
    for (int i = 0; i < 16; ++i) {
        if (rem & (1u << i)) {
            const int s = i >> 2, j = i & 3;
            const int cls = ((lane + (s << 6)) << 2) + j;
            const unsigned long long kk =
                ((unsigned long long)__float_as_uint(sc[i]) << 32) |
                (unsigned long long)(0xFFFFFFFFu - (unsigned)cls);
            if (kk > k1)      { k2 = k1; k1 = kk; }
            else if (kk > k2) { k2 = kk; }
        }
    }

    unsigned long long head = k1;              // lane's current best remaining
    int npop = 0;                              // pops served by this lane

    float cum = 0.f, pen = 0.f;
    int   k = 0;
    int   szb, last_idx;
    float V;

    while (true) {
        // wave argmax over packed keys (value order + stable tie-break in one cmp)
        unsigned long long wk = head;
        #pragma unroll
        for (int off = 32; off > 0; off >>= 1) {
            const unsigned long long ok = __shfl_xor(wk, off, 64);
            if (ok > wk) wk = ok;
        }
        const float val = __uint_as_float((unsigned)(wk >> 32));
        const int   idx = (int)(0xFFFFFFFFu - (unsigned)(wk & 0xFFFFFFFFull));

        // owner lane: mark extracted, refill head (O(1) for first two pops)
        const int ch = idx >> 2;
        if ((ch & 63) == lane) {
            const int slot = ((ch >> 6) << 2) | (idx & 3);
            rem  &= ~(1u << slot);
            memb |=  (1u << slot);
            if (npop == 0) {
                head = k2;                     // true 2nd-best of this lane
            } else {
                // rare: lane's 3rd+ pop -> full rescan over remaining slots
                unsigned long long best = 0ull;
                #pragma unroll
                for (int i = 0; i < 16; ++i) {
                    if (rem & (1u << i)) {
                        const int s = i >> 2, j = i & 3;
                        const int cls = ((lane + (s << 6)) << 2) + j;
                        const unsigned long long kk =
                            ((unsigned long long)__float_as_uint(sc[i]) << 32) |
                            (unsigned long long)(0xFFFFFFFFu - (unsigned)cls);
                        if (kk > best) best = kk;
                    }
                }
                head = best;                   // 0 sentinel if exhausted
            }
            ++npop;
        }
        last_idx = idx;

        const float pk   = (k < 64) ? __shfl(pl, k, 64) : penalties[k];
        const float penk = pen + pk;           // pcs[k]
        if (cum + val + penk <= tau) {
            cum += val; pen = penk; ++k;
            if (k >= C) {                      // all positions passed
                szb = C;
                V = (tau - (cum - val) - penk) / val;   // position C-1
                break;
            }
        } else {
            szb = k + 1;                       // first failure at k
            V = (tau - cum - penk) / val;      // cum_s - ord_s = cum
            break;
        }
    }

    // ---- randomized shrink, clamps ----
    int sizes = szb - ((uu >= V) ? 1 : 0);
    const bool full = (tau == 1.0f);
    if (full) sizes = C;
    if (sizes < 1) sizes = 1;
    const bool drop_last = (!full) && (sizes < szb);

    // ---- fused outputs: logits copy, mask, sizes ----
    float4* oL4 = reinterpret_cast<float4*>(outL + (size_t)row * C);
    float4* oM4 = reinterpret_cast<float4*>(outM + (size_t)row * C);
    #pragma unroll
    for (int s = 0; s < 4; ++s) {
        const int ch = lane + (s << 6);
        if (!valid[s]) continue;
        oL4[ch] = xv[s];
        float4 mk;
        float* mp = &mk.x;
        #pragma unroll
        for (int j = 0; j < 4; ++j) {
            const int slot = (s << 2) | j;
            const int cls  = (ch << 2) | j;
            const bool in_set = full ||
                (((memb >> slot) & 1u) && !(drop_last && cls == last_idx));
            mp[j] = in_set ? 1.0f : 0.0f;
        }
        oM4[ch] = mk;
    }
    if (lane == 0) outS[row] = (float)sizes;
}

extern "C" void kernel_launch(void* const* d_in, const int* in_sizes, int n_in,
                              void* d_out, int out_size, void* d_ws, size_t ws_size,
                              hipStream_t stream) {
    const float* logits    = (const float*)d_in[0];
    const float* penalties = (const float*)d_in[1];
    const float* u         = (const float*)d_in[2];
    const float* T         = (const float*)d_in[3];
    const float* Qhat      = (const float*)d_in[4];

    const int C = in_sizes[1];   // penalties: (1, C)
    const int B = in_sizes[2];   // u: (B,)

    float* out  = (float*)d_out;
    float* outL = out;                              // [B*C] logits pass-through
    float* outM = out + (size_t)B * C;              // [B*C] set mask as float
    float* outS = out + 2 * (size_t)B * C;          // [B]   sizes as float

    const int blocks = (B + 3) / 4;                 // 4 rows (waves) per block
    conformal_kernel<<<blocks, 256, 0, stream>>>(
        logits, penalties, u, T, Qhat, outL, outM, outS, B, C);
}